// Round 3
// baseline (223.778 us; speedup 1.0000x reference)
//
#include <hip/hip_runtime.h>
#include <math.h>

// BertBidafAttention B=16, CL=512, QL=64, H=768 — 6 lean kernels:
//   K0 k_split  : wth/wtl = split(W^T), qh/ql = split(q), qt = bf16(q^T)
//   K1 k_u_beta : u = q @ W (pure MFMA, split operands preloaded), beta = q @ bias
//   K2 k_s_sm   : s = c @ u^T + beta (c split once into DB LDS) + row softmax -> s1
//   K3 k_sm_cols: s2t = softmax_c(s)^T -> bf16 [b][64][512]
//   K4 k_t      : tt[b][h][q] = (s2^T @ c)^T (DB LDS c-transpose)
//   K5 k_fin    : a = s1@q, bvec = s1@t; out = [c, a, c*a, c*bvec] (no LDS, 768 blocks)
//
// Workspace compacted to 10.23 MB via lifetime aliasing (round-2 used 16 MB,
// which may have exceeded ws_size and killed the container):
//   region A [0,        2359296): wth,wtl (K0-K1)   -> s   (K2-K3)
//   region B [2359296,  5505024): qh,ql   (K0-K1)   -> s1, s2t (K2-K5)
//   qt       [5505024,  7077888): K0-K5
//   region C [7077888, 10223616): uh,ul   (K1-K2)   -> tt  (K4-K5)
//   beta     [10223616,10227712): K1-K2

#define B_  16
#define CL_ 512
#define QL_ 64
#define H_  768
#define M_  (B_ * CL_)   // 8192

typedef __attribute__((ext_vector_type(8))) short s8v;   // 8 bf16
typedef __attribute__((ext_vector_type(4))) float f4v;   // MFMA acc

__device__ __forceinline__ unsigned short bf16_rne(float x) {
    unsigned int u = __float_as_uint(x);
    u += 0x7fffu + ((u >> 16) & 1u);
    return (unsigned short)(u >> 16);
}
__device__ __forceinline__ float bf16_f(unsigned short h) {
    return __uint_as_float((unsigned int)h << 16);
}
__device__ __forceinline__ void split2(float x, unsigned short& h, unsigned short& l) {
    h = bf16_rne(x);
    l = bf16_rne(x - bf16_f(h));
}

// ---------- K0: split W (transposed) and q (row-major split + transposed bf16) ----------
__global__ __launch_bounds__(256) void k_split(const float* __restrict__ W,
    const float* __restrict__ q,
    unsigned short* __restrict__ wth, unsigned short* __restrict__ wtl,
    unsigned short* __restrict__ qh,  unsigned short* __restrict__ ql,
    unsigned short* __restrict__ qt)
{
    __shared__ float tile[64][68];
    const int t = threadIdx.x;
    const int r = t >> 4, c4 = (t & 15) * 4;
    if (blockIdx.x < 144) {
        // W[d][h] -> wth/wtl[h][d]
        const int d0 = (blockIdx.x % 12) * 64, h0 = (blockIdx.x / 12) * 64;
#pragma unroll
        for (int i = 0; i < 4; ++i)
            *(float4*)&tile[r + 16 * i][c4] = *(const float4*)&W[(size_t)(d0 + r + 16 * i) * H_ + h0 + c4];
        __syncthreads();
#pragma unroll
        for (int i = 0; i < 4; ++i) {
            const int hr = r + 16 * i;
            ushort4 hh, ll;
            split2(tile[c4 + 0][hr], hh.x, ll.x);
            split2(tile[c4 + 1][hr], hh.y, ll.y);
            split2(tile[c4 + 2][hr], hh.z, ll.z);
            split2(tile[c4 + 3][hr], hh.w, ll.w);
            *(ushort4*)&wth[(size_t)(h0 + hr) * H_ + d0 + c4] = hh;
            *(ushort4*)&wtl[(size_t)(h0 + hr) * H_ + d0 + c4] = ll;
        }
    } else {
        // q: rows m0..m0+63 (= batch idx&15), h-cols h0..h0+63
        const int idx = blockIdx.x - 144;
        const int m0 = (idx & 15) * 64, h0 = (idx >> 4) * 64;
        float4 v[4];
#pragma unroll
        for (int i = 0; i < 4; ++i) {
            v[i] = *(const float4*)&q[(size_t)(m0 + r + 16 * i) * H_ + h0 + c4];
            *(float4*)&tile[r + 16 * i][c4] = v[i];
        }
        __syncthreads();
        // row-major split (qh/ql) straight from regs
#pragma unroll
        for (int i = 0; i < 4; ++i) {
            const int row = m0 + r + 16 * i;
            ushort4 hh, ll;
            split2(v[i].x, hh.x, ll.x);
            split2(v[i].y, hh.y, ll.y);
            split2(v[i].z, hh.z, ll.z);
            split2(v[i].w, hh.w, ll.w);
            *(ushort4*)&qh[(size_t)row * H_ + h0 + c4] = hh;
            *(ushort4*)&ql[(size_t)row * H_ + h0 + c4] = ll;
        }
        // transposed single-bf16 qt[b][h][qr]
        const int b = idx & 15;
#pragma unroll
        for (int i = 0; i < 4; ++i) {
            const int hr = r + 16 * i;
            ushort4 hh;
            hh.x = bf16_rne(tile[c4 + 0][hr]);
            hh.y = bf16_rne(tile[c4 + 1][hr]);
            hh.z = bf16_rne(tile[c4 + 2][hr]);
            hh.w = bf16_rne(tile[c4 + 3][hr]);
            *(ushort4*)&qt[((size_t)b * H_ + h0 + hr) * QL_ + c4] = hh;
        }
    }
}

// ---------- K1: u = q @ W (pure MFMA from preloaded splits) + beta ----------
__global__ __launch_bounds__(256) void k_u_beta(
    const unsigned short* __restrict__ qh, const unsigned short* __restrict__ ql,
    const unsigned short* __restrict__ wth, const unsigned short* __restrict__ wtl,
    const float* __restrict__ q, const float* __restrict__ bias,
    unsigned short* __restrict__ uh, unsigned short* __restrict__ ul,
    float* __restrict__ beta)
{
    if (blockIdx.x >= 192) {
        const int row = (blockIdx.x - 192) * 4 + (threadIdx.x >> 6);
        const int lane = threadIdx.x & 63;
        float p = 0.f;
        for (int d = lane; d < H_; d += 64) p = fmaf(bias[d], q[(size_t)row * H_ + d], p);
#pragma unroll
        for (int o = 32; o; o >>= 1) p += __shfl_xor(p, o);
        if (lane == 0) beta[row] = p;
        return;
    }
    const int m0 = (blockIdx.x & 15) * 64, n0 = (blockIdx.x >> 4) * 64;
    const int t = threadIdx.x, w = t >> 6, lane = t & 63;
    const int fm = lane & 15, quad = lane >> 4;
    const int mrow = m0 + w * 16 + fm;
    f4v acc[4];
#pragma unroll
    for (int j = 0; j < 4; ++j) acc[j] = (f4v){0.f, 0.f, 0.f, 0.f};
    for (int k0 = 0; k0 < H_; k0 += 32) {
        const size_t ao = (size_t)mrow * H_ + k0 + quad * 8;
        const s8v fah = *(const s8v*)&qh[ao];
        const s8v fal = *(const s8v*)&ql[ao];
#pragma unroll
        for (int tn = 0; tn < 4; ++tn) {
            const size_t bo = (size_t)(n0 + tn * 16 + fm) * H_ + k0 + quad * 8;
            const s8v bh = *(const s8v*)&wth[bo];
            const s8v bl = *(const s8v*)&wtl[bo];
            acc[tn] = __builtin_amdgcn_mfma_f32_16x16x32_bf16(fah, bh, acc[tn], 0, 0, 0);
            acc[tn] = __builtin_amdgcn_mfma_f32_16x16x32_bf16(fah, bl, acc[tn], 0, 0, 0);
            acc[tn] = __builtin_amdgcn_mfma_f32_16x16x32_bf16(fal, bh, acc[tn], 0, 0, 0);
        }
    }
#pragma unroll
    for (int tn = 0; tn < 4; ++tn) {
        const int col = n0 + tn * 16 + fm;
#pragma unroll
        for (int r = 0; r < 4; ++r) {
            const int row = m0 + w * 16 + quad * 4 + r;
            unsigned short h, l; split2(acc[tn][r], h, l);
            uh[(size_t)row * H_ + col] = h;
            ul[(size_t)row * H_ + col] = l;
        }
    }
}

// ---------- K2: s = c @ u^T + beta (c split once -> DB LDS) + row softmax ----------
__global__ __launch_bounds__(256) void k_s_sm(const float* __restrict__ c,
    const unsigned short* __restrict__ uh, const unsigned short* __restrict__ ul,
    const float* __restrict__ beta, const int* __restrict__ q_mask,
    float* __restrict__ s, unsigned short* __restrict__ s1)
{
    __shared__ unsigned short chh[2][16][40], cll[2][16][40];
    __shared__ float sL[16][65];
    const int m0 = blockIdx.x * 16;
    const int batch = m0 >> 9;
    const int t = threadIdx.x, w = t >> 6, lane = t & 63;
    const int fm = lane & 15, quad = lane >> 4;
    const int srow = t >> 4, skk = (t & 15) * 2;   // staging: 16 rows x 32 k, 2 elems/thread
    f4v acc = (f4v){0.f, 0.f, 0.f, 0.f};

    float2 v = *(const float2*)&c[(size_t)(m0 + srow) * H_ + skk];
    int p = 0;
    for (int k0 = 0; k0 < H_; k0 += 32) {
        unsigned short h0s, l0s, h1s, l1s;
        split2(v.x, h0s, l0s); split2(v.y, h1s, l1s);
        *(ushort2*)&chh[p][srow][skk] = make_ushort2(h0s, h1s);
        *(ushort2*)&cll[p][srow][skk] = make_ushort2(l0s, l1s);
        __syncthreads();
        if (k0 + 32 < H_) v = *(const float2*)&c[(size_t)(m0 + srow) * H_ + k0 + 32 + skk];
        const s8v fah = *(const s8v*)&chh[p][fm][quad * 8];
        const s8v fal = *(const s8v*)&cll[p][fm][quad * 8];
        const size_t bo = (size_t)(batch * QL_ + w * 16 + fm) * H_ + k0 + quad * 8;
        const s8v bh = *(const s8v*)&uh[bo];
        const s8v bl = *(const s8v*)&ul[bo];
        acc = __builtin_amdgcn_mfma_f32_16x16x32_bf16(fah, bh, acc, 0, 0, 0);
        acc = __builtin_amdgcn_mfma_f32_16x16x32_bf16(fah, bl, acc, 0, 0, 0);
        acc = __builtin_amdgcn_mfma_f32_16x16x32_bf16(fal, bh, acc, 0, 0, 0);
        p ^= 1;
    }
    // epilogue: s, sL
    {
        const int col = w * 16 + fm;
        const float bb = beta[batch * QL_ + col];
#pragma unroll
        for (int r = 0; r < 4; ++r) {
            const int lr = quad * 4 + r;
            const float vv = acc[r] + bb;
            sL[lr][col] = vv;
            s[(size_t)(m0 + lr) * QL_ + col] = vv;
        }
    }
    __syncthreads();
    // row softmax over q (64 cols); wave w handles rows 4w..4w+3
    const bool qm = q_mask[batch * QL_ + lane] != 0;
#pragma unroll
    for (int rr = 0; rr < 4; ++rr) {
        const int lr = w * 4 + rr;
        const float x = qm ? sL[lr][lane] : -1e30f;
        float mx = x;
#pragma unroll
        for (int o = 32; o; o >>= 1) mx = fmaxf(mx, __shfl_xor(mx, o));
        const float e = __expf(x - mx);
        float sm = e;
#pragma unroll
        for (int o = 32; o; o >>= 1) sm += __shfl_xor(sm, o);
        s1[(size_t)(m0 + lr) * QL_ + lane] = bf16_rne(e / sm);
    }
}

// ---------- K3: s2^T = col softmax (c dim), transposed -> bf16 [b][q][c] ----------
__global__ __launch_bounds__(256) void k_sm_cols(const float* __restrict__ s,
    const int* __restrict__ c_mask, unsigned short* __restrict__ s2t)
{
    __shared__ float red[4];
    const int b = blockIdx.x >> 6, qi = blockIdx.x & 63;
    const int t = threadIdx.x;
    const float* sb = s + (size_t)b * CL_ * QL_ + qi;
    const int* cm = c_mask + b * CL_;
    float x0 = cm[t] ? sb[(size_t)t * QL_] : -1e30f;
    float x1 = cm[t + 256] ? sb[(size_t)(t + 256) * QL_] : -1e30f;
    float m = fmaxf(x0, x1);
#pragma unroll
    for (int o = 32; o; o >>= 1) m = fmaxf(m, __shfl_xor(m, o));
    if ((t & 63) == 0) red[t >> 6] = m;
    __syncthreads();
    m = fmaxf(fmaxf(red[0], red[1]), fmaxf(red[2], red[3]));
    __syncthreads();
    float e0 = __expf(x0 - m), e1 = __expf(x1 - m);
    float sm = e0 + e1;
#pragma unroll
    for (int o = 32; o; o >>= 1) sm += __shfl_xor(sm, o);
    if ((t & 63) == 0) red[t >> 6] = sm;
    __syncthreads();
    sm = red[0] + red[1] + red[2] + red[3];
    float inv = 1.f / sm;
    unsigned short* o = s2t + ((size_t)b * QL_ + qi) * CL_;
    o[t]       = bf16_rne(e0 * inv);
    o[t + 256] = bf16_rne(e1 * inv);
}

// ---------- K4: tt[b][h][q] = (s2^T @ c)^T (DB LDS c-transpose) ----------
__global__ __launch_bounds__(256) void k_t(const unsigned short* __restrict__ s2t,
    const float* __restrict__ c, unsigned short* __restrict__ tt)
{
    __shared__ unsigned short Bs[2][64][40];
    const int h0 = blockIdx.x * 64, b = blockIdx.y;
    const int t = threadIdx.x, w = t >> 6, lane = t & 63;
    const int fm = lane & 15, quad = lane >> 4;
    const int dd = t >> 3, hc = (t & 7) * 8;
    f4v acc[4];
#pragma unroll
    for (int j = 0; j < 4; ++j) acc[j] = (f4v){0.f, 0.f, 0.f, 0.f};

    const float* cp0 = &c[((size_t)b * CL_ + dd) * H_ + h0 + hc];
    float4 v0 = *(const float4*)cp0, v1 = *(const float4*)(cp0 + 4);
    int p = 0;
    for (int d0 = 0; d0 < CL_; d0 += 32) {
        const float xs[8] = {v0.x, v0.y, v0.z, v0.w, v1.x, v1.y, v1.z, v1.w};
#pragma unroll
        for (int j = 0; j < 8; ++j) Bs[p][hc + j][dd] = bf16_rne(xs[j]);
        __syncthreads();
        if (d0 + 32 < CL_) {
            const float* cp = &c[((size_t)b * CL_ + d0 + 32 + dd) * H_ + h0 + hc];
            v0 = *(const float4*)cp; v1 = *(const float4*)(cp + 4);
        }
        const s8v fb = *(const s8v*)&Bs[p][w * 16 + fm][quad * 8];
#pragma unroll
        for (int tm = 0; tm < 4; ++tm) {
            const s8v fa = *(const s8v*)&s2t[((size_t)b * QL_ + tm * 16 + fm) * CL_ + d0 + quad * 8];
            acc[tm] = __builtin_amdgcn_mfma_f32_16x16x32_bf16(fa, fb, acc[tm], 0, 0, 0);
        }
        p ^= 1;
    }
#pragma unroll
    for (int tm = 0; tm < 4; ++tm)
#pragma unroll
        for (int r = 0; r < 4; ++r)
            tt[((size_t)b * H_ + h0 + w * 16 + fm) * QL_ + tm * 16 + quad * 4 + r] = bf16_rne(acc[tm][r]);
}

// ---------- K5: finalize — a = s1@q, bvec = s1@t; out = [c, a, c*a, c*bvec] ----------
__global__ __launch_bounds__(256) void k_fin(const unsigned short* __restrict__ s1,
    const unsigned short* __restrict__ qt, const unsigned short* __restrict__ tt,
    const float* __restrict__ c, float* __restrict__ out)
{
    const int h0 = blockIdx.x * 64;
    const int c0 = blockIdx.y * 128;
    const int b  = blockIdx.z;
    const int t = threadIdx.x, w = t >> 6, lane = t & 63;
    const int fm = lane & 15, quad = lane >> 4;
    const int cbase = c0 + w * 32;
    f4v aa[2][4], bb[2][4];
#pragma unroll
    for (int i = 0; i < 2; ++i)
#pragma unroll
        for (int j = 0; j < 4; ++j) { aa[i][j] = (f4v){0.f, 0.f, 0.f, 0.f}; bb[i][j] = aa[i][j]; }
#pragma unroll
    for (int ks = 0; ks < 2; ++ks) {
        s8v fa[2], fq[4], ft[4];
#pragma unroll
        for (int tm = 0; tm < 2; ++tm)
            fa[tm] = *(const s8v*)&s1[(size_t)(b * CL_ + cbase + tm * 16 + fm) * QL_ + ks * 32 + quad * 8];
#pragma unroll
        for (int tn = 0; tn < 4; ++tn) {
            const size_t ro = ((size_t)b * H_ + h0 + tn * 16 + fm) * QL_ + ks * 32 + quad * 8;
            fq[tn] = *(const s8v*)&qt[ro];
            ft[tn] = *(const s8v*)&tt[ro];
        }
#pragma unroll
        for (int tm = 0; tm < 2; ++tm)
#pragma unroll
            for (int tn = 0; tn < 4; ++tn) {
                aa[tm][tn] = __builtin_amdgcn_mfma_f32_16x16x32_bf16(fa[tm], fq[tn], aa[tm][tn], 0, 0, 0);
                bb[tm][tn] = __builtin_amdgcn_mfma_f32_16x16x32_bf16(fa[tm], ft[tn], bb[tm][tn], 0, 0, 0);
            }
    }
#pragma unroll
    for (int tm = 0; tm < 2; ++tm)
#pragma unroll
        for (int tn = 0; tn < 4; ++tn) {
            const int h = h0 + tn * 16 + fm;
#pragma unroll
            for (int r = 0; r < 4; ++r) {
                const int crow = cbase + tm * 16 + quad * 4 + r;
                const float cv = c[((size_t)b * CL_ + crow) * H_ + h];
                const float av = aa[tm][tn][r], bv = bb[tm][tn][r];
                float* ob = out + (size_t)(b * CL_ + crow) * (4 * H_);
                ob[h]           = cv;
                ob[H_ + h]      = av;
                ob[2 * H_ + h]  = cv * av;
                ob[3 * H_ + h]  = cv * bv;
            }
        }
}

extern "C" void kernel_launch(void* const* d_in, const int* in_sizes, int n_in,
                              void* d_out, int out_size, void* d_ws, size_t ws_size,
                              hipStream_t stream) {
    const float* c      = (const float*)d_in[0];
    const float* q      = (const float*)d_in[1];
    const int*   c_mask = (const int*)d_in[2];
    const int*   q_mask = (const int*)d_in[3];
    const float* W      = (const float*)d_in[4];
    const float* bias   = (const float*)d_in[5];
    float* out = (float*)d_out;

    // workspace with lifetime aliasing — total 10227712 B (~9.8 MB)
    char* base = (char*)d_ws;
    // region A: wth/wtl (K0-K1), then s (K2-K3)
    unsigned short* wth  = (unsigned short*)(base);               // 1179648
    unsigned short* wtl  = (unsigned short*)(base + 1179648);     // 1179648
    float*          s    = (float*)(base);                        // 2097152 (aliases wth/wtl)
    // region B: qh/ql (K0-K1), then s1 + s2t (K2-K5)
    unsigned short* qh   = (unsigned short*)(base + 2359296);     // 1572864
    unsigned short* ql   = (unsigned short*)(base + 3932160);     // 1572864
    unsigned short* s1   = (unsigned short*)(base + 2359296);     // 1048576 (aliases qh)
    unsigned short* s2t  = (unsigned short*)(base + 3407872);     // 1048576 (aliases qh/ql tail)
    // qt: live K0-K5
    unsigned short* qt   = (unsigned short*)(base + 5505024);     // 1572864
    // region C: uh/ul (K1-K2), then tt (K4-K5)
    unsigned short* uh   = (unsigned short*)(base + 7077888);     // 1572864
    unsigned short* ul   = (unsigned short*)(base + 8650752);     // 1572864
    unsigned short* tt   = (unsigned short*)(base + 7077888);     // 1572864 (aliases uh)
    float*          beta = (float*)(base + 10223616);             // 4096

    dim3 blk(256);
    k_split  <<<dim3(336),        blk, 0, stream>>>(W, q, wth, wtl, qh, ql, qt);
    k_u_beta <<<dim3(192 + 256),  blk, 0, stream>>>(qh, ql, wth, wtl, q, bias, uh, ul, beta);
    k_s_sm   <<<dim3(512),        blk, 0, stream>>>(c, uh, ul, beta, q_mask, s, s1);
    k_sm_cols<<<dim3(B_ * QL_),   blk, 0, stream>>>(s, c_mask, s2t);
    k_t      <<<dim3(12, B_),     blk, 0, stream>>>(s2t, c, tt);
    k_fin    <<<dim3(12, 4, B_),  blk, 0, stream>>>(s1, qt, tt, c, out);
}

// Round 4
// 207.522 us; speedup vs baseline: 1.0783x; 1.0783x over previous
//
#include <hip/hip_runtime.h>
#include <math.h>

// BertBidafAttention B=16, CL=512, QL=64, H=768 — 3-launch pipeline:
//   K1 k_u_beta : u = q @ W (W split+transposed in LDS per block), beta = q @ bias
//   K2 k_s_sm   : s = c @ u^T + beta (c split once -> DB LDS), row softmax -> s1,
//                 epilogue writes s TRANSPOSED (sT[b][q][c], f32) for K3's colSM
//   K3 k_tfin3  : per (h0,b) block:
//                 A) colSM: softmax_c from contiguous sT rows -> s2L (LDS, bf16, XOR-swz)
//                 B) stage qT (LDS bf16)
//                 C) t-slice = (s2^T @ c) via MFMA (c transposed through DB LDS)
//                 D) out = [c, a, c*a, c*bvec] over all 512 c-rows (a = s1@q, bvec = s1@t)
//
// Rationale: rounds 0/1/3 fit dur ~= 207 + 3.3*launches regardless of body structure
// -> launch count is the lever. 6 -> 3 launches; kills k_split, k_sm_cols, k_t and
// the qt/s2t/tt global round-trips. Workspace: 6.3 MB.

#define B_  16
#define CL_ 512
#define QL_ 64
#define H_  768
#define M_  (B_ * CL_)   // 8192

typedef __attribute__((ext_vector_type(8))) short s8v;   // 8 bf16
typedef __attribute__((ext_vector_type(4))) float f4v;   // MFMA acc

__device__ __forceinline__ unsigned short bf16_rne(float x) {
    unsigned int u = __float_as_uint(x);
    u += 0x7fffu + ((u >> 16) & 1u);
    return (unsigned short)(u >> 16);
}
__device__ __forceinline__ float bf16_f(unsigned short h) {
    return __uint_as_float((unsigned int)h << 16);
}
__device__ __forceinline__ void split2(float x, unsigned short& h, unsigned short& l) {
    h = bf16_rne(x);
    l = bf16_rne(x - bf16_f(h));
}

// ---------- K1: u = q @ W (split-bf16; W staged+transposed+split in LDS)
//                + beta blocks (blockIdx.x >= 192) ----------
__global__ __launch_bounds__(256) void k_u_beta(const float* __restrict__ q,
    const float* __restrict__ W, const float* __restrict__ bias,
    unsigned short* __restrict__ uh, unsigned short* __restrict__ ul,
    float* __restrict__ beta)
{
    if (blockIdx.x >= 192) {
        // beta[row] = bias . q[row]
        const int row = (blockIdx.x - 192) * 4 + (threadIdx.x >> 6);
        const int lane = threadIdx.x & 63;
        float p = 0.f;
        for (int d = lane; d < H_; d += 64) p = fmaf(bias[d], q[(size_t)row * H_ + d], p);
#pragma unroll
        for (int o = 32; o; o >>= 1) p += __shfl_xor(p, o);
        if (lane == 0) beta[row] = p;
        return;
    }
    __shared__ unsigned short Wh[64][40], Wl[64][40];
    const int m0 = (blockIdx.x & 15) * 64, n0 = (blockIdx.x >> 4) * 64;
    const int t = threadIdx.x, w = t >> 6, lane = t & 63;
    const int fm = lane & 15, quad = lane >> 4;
    const int mrow = m0 + w * 16 + fm;
    const int dd = t >> 3, hc = (t & 7) * 8;
    f4v acc[4];
#pragma unroll
    for (int j = 0; j < 4; ++j) acc[j] = (f4v){0.f, 0.f, 0.f, 0.f};
    for (int k0 = 0; k0 < H_; k0 += 32) {
        const float* wp = &W[(size_t)(k0 + dd) * H_ + n0 + hc];
        const float4 v0 = *(const float4*)wp, v1 = *(const float4*)(wp + 4);
        const float* ap = &q[(size_t)mrow * H_ + k0 + quad * 8];
        const float4 a0 = *(const float4*)ap, a1 = *(const float4*)(ap + 4);
        const float as[8] = {a0.x, a0.y, a0.z, a0.w, a1.x, a1.y, a1.z, a1.w};
        s8v fah, fal;
#pragma unroll
        for (int j = 0; j < 8; ++j) { unsigned short h, l; split2(as[j], h, l); fah[j] = (short)h; fal[j] = (short)l; }
        const float ws[8] = {v0.x, v0.y, v0.z, v0.w, v1.x, v1.y, v1.z, v1.w};
        __syncthreads();   // protect previous iteration's LDS reads
#pragma unroll
        for (int j = 0; j < 8; ++j) {
            unsigned short h, l; split2(ws[j], h, l);
            Wh[hc + j][dd] = h; Wl[hc + j][dd] = l;
        }
        __syncthreads();
#pragma unroll
        for (int tn = 0; tn < 4; ++tn) {
            const s8v bh = *(const s8v*)&Wh[tn * 16 + fm][quad * 8];
            const s8v bl = *(const s8v*)&Wl[tn * 16 + fm][quad * 8];
            acc[tn] = __builtin_amdgcn_mfma_f32_16x16x32_bf16(fah, bh, acc[tn], 0, 0, 0);
            acc[tn] = __builtin_amdgcn_mfma_f32_16x16x32_bf16(fah, bl, acc[tn], 0, 0, 0);
            acc[tn] = __builtin_amdgcn_mfma_f32_16x16x32_bf16(fal, bh, acc[tn], 0, 0, 0);
        }
    }
#pragma unroll
    for (int tn = 0; tn < 4; ++tn) {
        const int col = n0 + tn * 16 + fm;
#pragma unroll
        for (int r = 0; r < 4; ++r) {
            const int row = m0 + w * 16 + quad * 4 + r;
            unsigned short h, l; split2(acc[tn][r], h, l);
            uh[(size_t)row * H_ + col] = h;
            ul[(size_t)row * H_ + col] = l;
        }
    }
}

// ---------- K2: s = c @ u^T + beta (c split once -> DB LDS) + row softmax -> s1
//                epilogue writes sT[b][q][c] (f32, transposed via sL) ----------
__global__ __launch_bounds__(256) void k_s_sm(const float* __restrict__ c,
    const unsigned short* __restrict__ uh, const unsigned short* __restrict__ ul,
    const float* __restrict__ beta, const int* __restrict__ q_mask,
    float* __restrict__ sT, unsigned short* __restrict__ s1)
{
    __shared__ unsigned short chh[2][16][40], cll[2][16][40];
    __shared__ float sL[16][65];
    const int m0 = blockIdx.x * 16;
    const int batch = m0 >> 9;
    const int cloc = m0 & (CL_ - 1);
    const int t = threadIdx.x, w = t >> 6, lane = t & 63;
    const int fm = lane & 15, quad = lane >> 4;
    const int srow = t >> 4, skk = (t & 15) * 2;   // staging: 16 rows x 32 k, 2 elems/thread
    f4v acc = (f4v){0.f, 0.f, 0.f, 0.f};

    float2 v = *(const float2*)&c[(size_t)(m0 + srow) * H_ + skk];
    int p = 0;
    for (int k0 = 0; k0 < H_; k0 += 32) {
        unsigned short h0s, l0s, h1s, l1s;
        split2(v.x, h0s, l0s); split2(v.y, h1s, l1s);
        *(ushort2*)&chh[p][srow][skk] = make_ushort2(h0s, h1s);
        *(ushort2*)&cll[p][srow][skk] = make_ushort2(l0s, l1s);
        __syncthreads();
        if (k0 + 32 < H_) v = *(const float2*)&c[(size_t)(m0 + srow) * H_ + k0 + 32 + skk];
        const s8v fah = *(const s8v*)&chh[p][fm][quad * 8];
        const s8v fal = *(const s8v*)&cll[p][fm][quad * 8];
        const size_t bo = (size_t)(batch * QL_ + w * 16 + fm) * H_ + k0 + quad * 8;
        const s8v bh = *(const s8v*)&uh[bo];
        const s8v bl = *(const s8v*)&ul[bo];
        acc = __builtin_amdgcn_mfma_f32_16x16x32_bf16(fah, bh, acc, 0, 0, 0);
        acc = __builtin_amdgcn_mfma_f32_16x16x32_bf16(fah, bl, acc, 0, 0, 0);
        acc = __builtin_amdgcn_mfma_f32_16x16x32_bf16(fal, bh, acc, 0, 0, 0);
        p ^= 1;
    }
    // epilogue: fill sL tile
    {
        const int col = w * 16 + fm;
        const float bb = beta[batch * QL_ + col];
#pragma unroll
        for (int r = 0; r < 4; ++r) {
            const int lr = quad * 4 + r;
            sL[lr][col] = acc[r] + bb;
        }
    }
    __syncthreads();
    // row softmax over q (64 cols); wave w handles rows 4w..4w+3
    const bool qm = q_mask[batch * QL_ + lane] != 0;
#pragma unroll
    for (int rr = 0; rr < 4; ++rr) {
        const int lr = w * 4 + rr;
        const float x = qm ? sL[lr][lane] : -1e30f;
        float mx = x;
#pragma unroll
        for (int o = 32; o; o >>= 1) mx = fmaxf(mx, __shfl_xor(mx, o));
        const float e = __expf(x - mx);
        float sm = e;
#pragma unroll
        for (int o = 32; o; o >>= 1) sm += __shfl_xor(sm, o);
        s1[(size_t)(m0 + lr) * QL_ + lane] = bf16_rne(e / sm);
    }
    // transposed raw-s write: sT[b][q][cloc..cloc+15] (coalesced float4 per 4 lanes)
    {
        const int qq = t >> 2, c4o = (t & 3) * 4;
        float4 ov;
        ov.x = sL[c4o + 0][qq];
        ov.y = sL[c4o + 1][qq];
        ov.z = sL[c4o + 2][qq];
        ov.w = sL[c4o + 3][qq];
        *(float4*)&sT[((size_t)batch * QL_ + qq) * CL_ + cloc + c4o] = ov;
    }
}

// ---------- K3: fused colSM + t + finalize, one block per (h0, b) ----------
__global__ __launch_bounds__(256) void k_tfin3(const float* __restrict__ sT,
    const unsigned short* __restrict__ s1, const float* __restrict__ q,
    const float* __restrict__ c, const int* __restrict__ c_mask,
    float* __restrict__ out)
{
    __shared__ unsigned short s2L[64 * 512];   // colSM result, [q][c] bf16, XOR-swizzled (64 KB)
    __shared__ unsigned short qT[64][72];      // q^T bf16 (h x q)
    __shared__ unsigned short tT[64][72];      // t   bf16 (h x q)
    __shared__ unsigned short Bs[2][64][40];   // c^T staging tile (h x d), double-buffered
    const int h0 = blockIdx.x * 64;
    const int b  = blockIdx.y;
    const int t = threadIdx.x, w = t >> 6, lane = t & 63;
    const int fm = lane & 15, quad = lane >> 4;

    // ---- phase A: column softmax (over c) for batch b -> s2L ----
    {
        const int cbase8 = lane * 8;
        int cm8[8];
#pragma unroll
        for (int j = 0; j < 8; ++j) cm8[j] = c_mask[b * CL_ + cbase8 + j];
        const float* stb = sT + (size_t)b * QL_ * CL_;
        for (int qi = 0; qi < 16; ++qi) {
            const int qq = w * 16 + qi;
            const float* sr = stb + (size_t)qq * CL_ + cbase8;
            const float4 v0 = *(const float4*)sr, v1 = *(const float4*)(sr + 4);
            float x[8] = {v0.x, v0.y, v0.z, v0.w, v1.x, v1.y, v1.z, v1.w};
#pragma unroll
            for (int j = 0; j < 8; ++j) x[j] = cm8[j] ? x[j] : -1e30f;
            float m = x[0];
#pragma unroll
            for (int j = 1; j < 8; ++j) m = fmaxf(m, x[j]);
#pragma unroll
            for (int o = 32; o; o >>= 1) m = fmaxf(m, __shfl_xor(m, o));
            float e[8], sm = 0.f;
#pragma unroll
            for (int j = 0; j < 8; ++j) { e[j] = __expf(x[j] - m); sm += e[j]; }
#pragma unroll
            for (int o = 32; o; o >>= 1) sm += __shfl_xor(sm, o);
            const float inv = 1.f / sm;
            s8v sv;
#pragma unroll
            for (int j = 0; j < 8; ++j) sv[j] = (short)bf16_rne(e[j] * inv);
            const int boff = ((qq * 512 + cbase8) * 2) ^ ((qq & 7) << 4);
            *(s8v*)((char*)s2L + boff) = sv;
        }
    }

    // ---- phase B: stage q^T ----
    {
        const int r = t >> 4, c4 = (t & 15) * 4;
#pragma unroll
        for (int i = 0; i < 4; ++i) {
            const int qr = r + 16 * i;
            const float4 v = *(const float4*)&q[((size_t)b * QL_ + qr) * H_ + h0 + c4];
            qT[c4 + 0][qr] = bf16_rne(v.x);
            qT[c4 + 1][qr] = bf16_rne(v.y);
            qT[c4 + 2][qr] = bf16_rne(v.z);
            qT[c4 + 3][qr] = bf16_rne(v.w);
        }
    }

    // ---- phase C: t-slice = (s2^T @ c) for this h0 (DB LDS c-transpose) ----
    {
        const int dd = t >> 3, hc = (t & 7) * 8;
        f4v acc[4];
#pragma unroll
        for (int j = 0; j < 4; ++j) acc[j] = (f4v){0.f, 0.f, 0.f, 0.f};
        const float* cp0 = &c[((size_t)b * CL_ + dd) * H_ + h0 + hc];
        float4 v0 = *(const float4*)cp0, v1 = *(const float4*)(cp0 + 4);
        int p = 0;
        for (int d0 = 0; d0 < CL_; d0 += 32) {
            const float xs[8] = {v0.x, v0.y, v0.z, v0.w, v1.x, v1.y, v1.z, v1.w};
#pragma unroll
            for (int j = 0; j < 8; ++j) Bs[p][hc + j][dd] = bf16_rne(xs[j]);
            __syncthreads();   // also orders phase-A/B LDS writes before first reads
            if (d0 + 32 < CL_) {
                const float* cp = &c[((size_t)b * CL_ + d0 + 32 + dd) * H_ + h0 + hc];
                v0 = *(const float4*)cp; v1 = *(const float4*)(cp + 4);
            }
            const s8v fb = *(const s8v*)&Bs[p][w * 16 + fm][quad * 8];
#pragma unroll
            for (int tm = 0; tm < 4; ++tm) {
                const int boff = (((tm * 16 + fm) * 512 + d0 + quad * 8) * 2) ^ ((fm & 7) << 4);
                const s8v fa = *(const s8v*)((const char*)s2L + boff);
                acc[tm] = __builtin_amdgcn_mfma_f32_16x16x32_bf16(fa, fb, acc[tm], 0, 0, 0);
            }
            p ^= 1;
        }
#pragma unroll
        for (int tm = 0; tm < 4; ++tm)
#pragma unroll
            for (int r = 0; r < 4; ++r)
                tT[w * 16 + fm][tm * 16 + quad * 4 + r] = bf16_rne(acc[tm][r]);
    }
    __syncthreads();

    // ---- phase D: finalize all 512 c-rows (2 chunks of 256) ----
    for (int cc = 0; cc < 2; ++cc) {
        const int cbase = cc * 256 + w * 64;
        f4v aa[4][4], bb[4][4];
#pragma unroll
        for (int i = 0; i < 4; ++i)
#pragma unroll
            for (int j = 0; j < 4; ++j) { aa[i][j] = (f4v){0.f, 0.f, 0.f, 0.f}; bb[i][j] = aa[i][j]; }
#pragma unroll
        for (int ks = 0; ks < 2; ++ks) {
            s8v fa[4], fq[4], ft[4];
#pragma unroll
            for (int tm = 0; tm < 4; ++tm)
                fa[tm] = *(const s8v*)&s1[(size_t)(b * CL_ + cbase + tm * 16 + fm) * QL_ + ks * 32 + quad * 8];
#pragma unroll
            for (int tn = 0; tn < 4; ++tn) {
                fq[tn] = *(const s8v*)&qT[tn * 16 + fm][ks * 32 + quad * 8];
                ft[tn] = *(const s8v*)&tT[tn * 16 + fm][ks * 32 + quad * 8];
            }
#pragma unroll
            for (int tm = 0; tm < 4; ++tm)
#pragma unroll
                for (int tn = 0; tn < 4; ++tn) {
                    aa[tm][tn] = __builtin_amdgcn_mfma_f32_16x16x32_bf16(fa[tm], fq[tn], aa[tm][tn], 0, 0, 0);
                    bb[tm][tn] = __builtin_amdgcn_mfma_f32_16x16x32_bf16(fa[tm], ft[tn], bb[tm][tn], 0, 0, 0);
                }
        }
#pragma unroll
        for (int tm = 0; tm < 4; ++tm)
#pragma unroll
            for (int tn = 0; tn < 4; ++tn) {
                const int h = h0 + tn * 16 + fm;
#pragma unroll
                for (int r = 0; r < 4; ++r) {
                    const int crow = cbase + tm * 16 + quad * 4 + r;
                    const float cv = c[((size_t)b * CL_ + crow) * H_ + h];
                    const float av = aa[tm][tn][r], bv = bb[tm][tn][r];
                    float* ob = out + (size_t)(b * CL_ + crow) * (4 * H_);
                    ob[h]           = cv;
                    ob[H_ + h]      = av;
                    ob[2 * H_ + h]  = cv * av;
                    ob[3 * H_ + h]  = cv * bv;
                }
            }
    }
}

extern "C" void kernel_launch(void* const* d_in, const int* in_sizes, int n_in,
                              void* d_out, int out_size, void* d_ws, size_t ws_size,
                              hipStream_t stream) {
    const float* c      = (const float*)d_in[0];
    const float* q      = (const float*)d_in[1];
    const int*   c_mask = (const int*)d_in[2];
    const int*   q_mask = (const int*)d_in[3];
    const float* W      = (const float*)d_in[4];
    const float* bias   = (const float*)d_in[5];
    float* out = (float*)d_out;

    // workspace — total 6295552 B (~6.0 MB)
    char* base = (char*)d_ws;
    unsigned short* uh   = (unsigned short*)(base);               // 1572864
    unsigned short* ul   = (unsigned short*)(base + 1572864);     // 1572864
    float*          beta = (float*)(base + 3145728);              // 4096
    float*          sT   = (float*)(base + 3149824);              // 2097152 (f32 [16][64][512])
    unsigned short* s1   = (unsigned short*)(base + 5246976);     // 1048576

    dim3 blk(256);
    k_u_beta <<<dim3(192 + 256),  blk, 0, stream>>>(q, W, bias, uh, ul, beta);
    k_s_sm   <<<dim3(512),        blk, 0, stream>>>(c, uh, ul, beta, q_mask, sT, s1);
    k_tfin3  <<<dim3(12, 16),     blk, 0, stream>>>(sT, s1, q, c, c_mask, out);
}